// Round 1
// baseline (4856.192 us; speedup 1.0000x reference)
//
#include <hip/hip_runtime.h>
#include <math.h>

namespace {

constexpr int NB    = 8;     // batch
constexpr int CH    = 192;
constexpr int IMG   = 128;
constexpr int SH    = 4;     // shift
constexpr int NH    = 4;     // heads
constexpr int HD    = 48;    // head dim
constexpr int L     = 64;    // tokens per window
constexpr int NWIN  = 256;   // windows per image
constexpr int HID   = 768;
constexpr float SCALE = 0.14433756729740643f; // 1/sqrt(48)

__device__ __forceinline__ int token_region(int wh, int ww, int tok) {
    const int hh = wh * 8 + (tok >> 3);
    const int wp = ww * 8 + (tok & 7);
    const int hr = (hh < IMG - 8) ? 0 : ((hh < IMG - 4) ? 1 : 2);
    const int wr = (wp < IMG - 8) ? 0 : ((wp < IMG - 4) ? 1 : 2);
    return hr * 3 + wr;
}

__device__ __forceinline__ void layernorm_win(
    float (* __restrict__ src)[CH + 1], float (* __restrict__ dst)[CH + 1],
    float (* __restrict__ red)[8],
    const float* __restrict__ g, const float* __restrict__ be, int tid)
{
    const int t = tid & 63, quad = tid >> 6;
    float s = 0.f, s2 = 0.f;
    #pragma unroll 8
    for (int i = 0; i < 48; ++i) {
        const float v = src[t][quad * 48 + i];
        s += v; s2 += v * v;
    }
    red[t][quad] = s;
    red[t][4 + quad] = s2;
    __syncthreads();
    const float mu = (red[t][0] + red[t][1] + red[t][2] + red[t][3]) * (1.f / 192.f);
    const float ms = (red[t][4] + red[t][5] + red[t][6] + red[t][7]) * (1.f / 192.f);
    const float rsig = rsqrtf(ms - mu * mu + 1e-5f);
    #pragma unroll 8
    for (int cc = 0; cc < 48; ++cc) {
        const int c = cc * 4 + quad;
        dst[t][c] = (src[t][c] - mu) * rsig * g[c] + be[c];
    }
    __syncthreads();
}

__global__ __launch_bounds__(256)
void swin_fused(const float* __restrict__ x,
                const float* __restrict__ bias_tab,
                const float* __restrict__ qkv_w, const float* __restrict__ qkv_b,
                const float* __restrict__ proj_w, const float* __restrict__ proj_b,
                const float* __restrict__ n1g, const float* __restrict__ n1b,
                const float* __restrict__ n2g, const float* __restrict__ n2b,
                const float* __restrict__ w1, const float* __restrict__ b1,
                const float* __restrict__ w2, const float* __restrict__ b2,
                float* __restrict__ out)
{
    __shared__ float s_x1[L][CH + 1];        // shortcut -> x1 accumulator
    __shared__ float s_xn[L][CH + 1];        // LN1 out; later LN2 out
    __shared__ float s_qkv[3][L][HD + 1];    // q,k,v per head; reused as MLP hidden chunk
    __shared__ float s_sc[L][L + 1];         // attention scores
    __shared__ float s_red[L][8];            // reductions

    const int tid  = threadIdx.x;
    const int wid  = blockIdx.x;
    const int b    = wid >> 8;      // / 256
    const int nwin = wid & 255;
    const int wh   = nwin >> 4, ww = nwin & 15;

    const int t    = tid & 63;
    const int quad = tid >> 6;
    const int ty   = t >> 3, tx = t & 7;
    const int oh   = (wh * 8 + ty + SH) & (IMG - 1);
    const int ow   = (ww * 8 + tx + SH) & (IMG - 1);

    // ---- load shifted window (shortcut) ----
    #pragma unroll 8
    for (int cc = 0; cc < CH / 4; ++cc) {
        const int c = cc * 4 + quad;
        s_x1[t][c] = x[((b * CH + c) * IMG + oh) * IMG + ow];
    }
    __syncthreads();

    // ---- LN1 ----
    layernorm_win(s_x1, s_xn, s_red, n1g, n1b, tid);

    // ---- attention, head by head ----
    for (int h = 0; h < NH; ++h) {
        // qkv GEMM: 64 x 144 (q|k|v) x 192
        {
            const int j16 = tid & 15;
            const int t0  = (tid >> 4) * 4;
            float acc[4][9];
            #pragma unroll
            for (int i = 0; i < 4; ++i)
                #pragma unroll
                for (int s = 0; s < 9; ++s) acc[i][s] = 0.f;
            int gcol[9];
            #pragma unroll
            for (int s = 0; s < 9; ++s) {
                const int scol = j16 + 16 * s;   // 0..143
                gcol[s] = (scol / 48) * CH + h * HD + (scol % 48);
            }
            #pragma unroll 2
            for (int c = 0; c < CH; ++c) {
                float xv[4];
                #pragma unroll
                for (int i = 0; i < 4; ++i) xv[i] = s_xn[t0 + i][c];
                const float* wr = qkv_w + c * (3 * CH);
                #pragma unroll
                for (int s = 0; s < 9; ++s) {
                    const float wv = wr[gcol[s]];
                    #pragma unroll
                    for (int i = 0; i < 4; ++i) acc[i][s] = fmaf(xv[i], wv, acc[i][s]);
                }
            }
            #pragma unroll
            for (int s = 0; s < 9; ++s) {
                const int scol = j16 + 16 * s;
                const int arr = scol / 48, d = scol % 48;
                const float bb = qkv_b[gcol[s]];
                #pragma unroll
                for (int i = 0; i < 4; ++i)
                    s_qkv[arr][t0 + i][d] = acc[i][s] + bb;
            }
        }
        __syncthreads();

        // scores = q@k^T * scale + bias/mask
        {
            const int r  = tid >> 2;
            const int j0 = (tid & 3) * 16;
            float acc[16];
            #pragma unroll
            for (int jj = 0; jj < 16; ++jj) acc[jj] = 0.f;
            #pragma unroll 4
            for (int d = 0; d < HD; ++d) {
                const float qv = s_qkv[0][r][d];
                #pragma unroll
                for (int jj = 0; jj < 16; ++jj)
                    acc[jj] = fmaf(qv, s_qkv[1][j0 + jj][d], acc[jj]);
            }
            const int regr = token_region(wh, ww, r);
            const int ry = r >> 3, rx = r & 7;
            #pragma unroll
            for (int jj = 0; jj < 16; ++jj) {
                const int j = j0 + jj;
                float biasv;
                if (token_region(wh, ww, j) != regr) {
                    biasv = -100.f;
                } else {
                    const int ridx = (ry - (j >> 3) + 7) * 15 + (rx - (j & 7) + 7);
                    biasv = bias_tab[h * 225 + ridx];
                }
                s_sc[r][j] = acc[jj] * SCALE + biasv;
            }
        }
        __syncthreads();

        // softmax (max + exp; normalization folded into PV)
        {
            const int rr = tid & 63;
            const int p  = tid >> 6;
            float m = -1e30f;
            #pragma unroll
            for (int jj = 0; jj < 16; ++jj) m = fmaxf(m, s_sc[rr][p * 16 + jj]);
            s_red[rr][p] = m;
            __syncthreads();
            m = fmaxf(fmaxf(s_red[rr][0], s_red[rr][1]),
                      fmaxf(s_red[rr][2], s_red[rr][3]));
            float s = 0.f;
            #pragma unroll
            for (int jj = 0; jj < 16; ++jj) {
                const float e = __expf(s_sc[rr][p * 16 + jj] - m);
                s_sc[rr][p * 16 + jj] = e;
                s += e;
            }
            s_red[rr][4 + p] = s;
        }
        __syncthreads();

        // out_h = softmax @ v  (into s_qkv[0], q no longer needed)
        {
            const int i  = tid & 63;
            const int p  = tid >> 6;
            const int d0 = p * 12;
            const float inv = 1.f / (s_red[i][4] + s_red[i][5] + s_red[i][6] + s_red[i][7]);
            float acc[12];
            #pragma unroll
            for (int dd = 0; dd < 12; ++dd) acc[dd] = 0.f;
            #pragma unroll 2
            for (int j = 0; j < L; ++j) {
                const float pv = s_sc[i][j];
                #pragma unroll
                for (int dd = 0; dd < 12; ++dd)
                    acc[dd] = fmaf(pv, s_qkv[2][j][d0 + dd], acc[dd]);
            }
            #pragma unroll
            for (int dd = 0; dd < 12; ++dd)
                s_qkv[0][i][d0 + dd] = acc[dd] * inv;
        }
        __syncthreads();

        // proj: x1 += out_h @ proj_w[h*48:(h+1)*48, :]
        {
            const int j16 = tid & 15;
            const int t0  = (tid >> 4) * 4;
            float acc[4][12];
            #pragma unroll
            for (int i = 0; i < 4; ++i)
                #pragma unroll
                for (int s = 0; s < 12; ++s) acc[i][s] = 0.f;
            #pragma unroll 2
            for (int d = 0; d < HD; ++d) {
                float ov[4];
                #pragma unroll
                for (int i = 0; i < 4; ++i) ov[i] = s_qkv[0][t0 + i][d];
                const float* wr = proj_w + (h * HD + d) * CH;
                #pragma unroll
                for (int s = 0; s < 12; ++s) {
                    const float wv = wr[j16 + 16 * s];
                    #pragma unroll
                    for (int i = 0; i < 4; ++i) acc[i][s] = fmaf(ov[i], wv, acc[i][s]);
                }
            }
            #pragma unroll
            for (int s = 0; s < 12; ++s)
                #pragma unroll
                for (int i = 0; i < 4; ++i)
                    s_x1[t0 + i][j16 + 16 * s] += acc[i][s];
        }
        __syncthreads();
    }

    // ---- + proj bias ----
    #pragma unroll 8
    for (int cc = 0; cc < CH / 4; ++cc) {
        const int c = cc * 4 + quad;
        s_x1[t][c] += proj_b[c];
    }
    __syncthreads();

    // ---- LN2 ----
    layernorm_win(s_x1, s_xn, s_red, n2g, n2b, tid);

    // ---- MLP in hidden chunks of 128 ----
    float (*s_h)[129] = reinterpret_cast<float (*)[129]>(&s_qkv[0][0][0]);
    for (int ch = 0; ch < HID / 128; ++ch) {
        const int u0 = ch * 128;
        // hidden = gelu(xn @ w1 + b1)
        {
            const int j16 = tid & 15;
            const int t0  = (tid >> 4) * 4;
            float acc[4][8];
            #pragma unroll
            for (int i = 0; i < 4; ++i)
                #pragma unroll
                for (int s = 0; s < 8; ++s) acc[i][s] = 0.f;
            #pragma unroll 2
            for (int c = 0; c < CH; ++c) {
                float xv[4];
                #pragma unroll
                for (int i = 0; i < 4; ++i) xv[i] = s_xn[t0 + i][c];
                const float* wr = w1 + c * HID + u0;
                #pragma unroll
                for (int s = 0; s < 8; ++s) {
                    const float wv = wr[j16 + 16 * s];
                    #pragma unroll
                    for (int i = 0; i < 4; ++i) acc[i][s] = fmaf(xv[i], wv, acc[i][s]);
                }
            }
            #pragma unroll
            for (int s = 0; s < 8; ++s) {
                const int u = j16 + 16 * s;
                const float bb = b1[u0 + u];
                #pragma unroll
                for (int i = 0; i < 4; ++i) {
                    const float vh = acc[i][s] + bb;
                    s_h[t0 + i][u] = 0.5f * vh * (1.f + erff(vh * 0.70710678118654752f));
                }
            }
        }
        __syncthreads();
        // x1 += hidden @ w2
        {
            const int j16 = tid & 15;
            const int t0  = (tid >> 4) * 4;
            float acc[4][12];
            #pragma unroll
            for (int i = 0; i < 4; ++i)
                #pragma unroll
                for (int s = 0; s < 12; ++s) acc[i][s] = 0.f;
            #pragma unroll 2
            for (int u = 0; u < 128; ++u) {
                float hv[4];
                #pragma unroll
                for (int i = 0; i < 4; ++i) hv[i] = s_h[t0 + i][u];
                const float* wr = w2 + (u0 + u) * CH;
                #pragma unroll
                for (int s = 0; s < 12; ++s) {
                    const float wv = wr[j16 + 16 * s];
                    #pragma unroll
                    for (int i = 0; i < 4; ++i) acc[i][s] = fmaf(hv[i], wv, acc[i][s]);
                }
            }
            #pragma unroll
            for (int s = 0; s < 12; ++s)
                #pragma unroll
                for (int i = 0; i < 4; ++i)
                    s_x1[t0 + i][j16 + 16 * s] += acc[i][s];
        }
        __syncthreads();
    }

    // ---- write out (+ mlp b2), window-reverse + roll back ----
    #pragma unroll 8
    for (int cc = 0; cc < CH / 4; ++cc) {
        const int c = cc * 4 + quad;
        out[((b * CH + c) * IMG + oh) * IMG + ow] = s_x1[t][c] + b2[c];
    }
}

} // namespace

extern "C" void kernel_launch(void* const* d_in, const int* in_sizes, int n_in,
                              void* d_out, int out_size, void* d_ws, size_t ws_size,
                              hipStream_t stream) {
    (void)in_sizes; (void)n_in; (void)d_ws; (void)ws_size; (void)out_size;
    const float* x   = (const float*)d_in[0];
    const float* bt  = (const float*)d_in[1];
    const float* qw  = (const float*)d_in[2];
    const float* qb  = (const float*)d_in[3];
    const float* pw  = (const float*)d_in[4];
    const float* pb  = (const float*)d_in[5];
    const float* g1  = (const float*)d_in[6];
    const float* be1 = (const float*)d_in[7];
    const float* g2  = (const float*)d_in[8];
    const float* be2 = (const float*)d_in[9];
    const float* w1  = (const float*)d_in[10];
    const float* bb1 = (const float*)d_in[11];
    const float* w2  = (const float*)d_in[12];
    const float* bb2 = (const float*)d_in[13];

    swin_fused<<<NB * NWIN, 256, 0, stream>>>(
        x, bt, qw, qb, pw, pb, g1, be1, g2, be2, w1, bb1, w2, bb2,
        (float*)d_out);
}

// Round 2
// 453.097 us; speedup vs baseline: 10.7178x; 10.7178x over previous
//
#include <hip/hip_runtime.h>
#include <math.h>

namespace {

constexpr int NB    = 8;
constexpr int CH    = 192;
constexpr int IMG   = 128;
constexpr int NWIN  = 256;
constexpr float SCALE = 0.14433756729740643f; // 1/sqrt(48)

// frag-major weight buffer offsets (in ushort elements)
constexpr int O_QKV  = 0;        // 4*9*6*512   = 110592
constexpr int O_PROJ = 110592;   // 12*6*512    =  36864
constexpr int O_W1   = 147456;   // 48*6*512    = 147456
constexpr int O_W2   = 294912;   // 12*24*512   = 147456
constexpr int W_TOT  = 442368;

typedef __bf16 bf16x8 __attribute__((ext_vector_type(8)));
typedef float  f32x4  __attribute__((ext_vector_type(4)));

__device__ __forceinline__ unsigned short f2b(float f) {
    union { float f; unsigned int u; } a; a.f = f;
    unsigned int r = a.u + 0x7FFFu + ((a.u >> 16) & 1u);
    return (unsigned short)(r >> 16);
}
__device__ __forceinline__ float b2f(unsigned short h) {
    union { unsigned int u; float f; } a; a.u = ((unsigned int)h) << 16;
    return a.f;
}

__device__ __forceinline__ bf16x8 ldfrag(const unsigned short* p) {
    return *reinterpret_cast<const bf16x8*>(p);
}

__device__ __forceinline__ f32x4 MFMA(bf16x8 a, bf16x8 b, f32x4 c) {
    return __builtin_amdgcn_mfma_f32_16x16x32_bf16(a, b, c, 0, 0, 0);
}

__device__ __forceinline__ int token_region(int wh, int ww, int tok) {
    const int hh = wh * 8 + (tok >> 3);
    const int wp = ww * 8 + (tok & 7);
    const int hr = (hh < IMG - 8) ? 0 : ((hh < IMG - 4) ? 1 : 2);
    const int wr = (wp < IMG - 8) ? 0 : ((wp < IMG - 4) ? 1 : 2);
    return hr * 3 + wr;
}

__device__ __forceinline__ float gelu_f(float v) {
    float y = 1.5957691216057308f * (v + 0.044715f * v * v * v); // 2*z
    y = fminf(fmaxf(y, -40.f), 40.f);
    const float e = __expf(y);
    const float t = (e - 1.f) * __builtin_amdgcn_rcpf(e + 1.f);  // tanh(z)
    return 0.5f * v * (1.f + t);
}

__device__ __forceinline__ void unpack8(uint4 r, float* v) {
    v[0] = b2f((unsigned short)(r.x & 0xFFFF)); v[1] = b2f((unsigned short)(r.x >> 16));
    v[2] = b2f((unsigned short)(r.y & 0xFFFF)); v[3] = b2f((unsigned short)(r.y >> 16));
    v[4] = b2f((unsigned short)(r.z & 0xFFFF)); v[5] = b2f((unsigned short)(r.z >> 16));
    v[6] = b2f((unsigned short)(r.w & 0xFFFF)); v[7] = b2f((unsigned short)(r.w >> 16));
}

// ---- weight conversion: fp32 -> bf16 frag-major in d_ws ----
__global__ __launch_bounds__(256)
void convert_weights(const float* __restrict__ qkv_w, const float* __restrict__ proj_w,
                     const float* __restrict__ w1, const float* __restrict__ w2,
                     unsigned short* __restrict__ wf)
{
    const int id = blockIdx.x * 256 + threadIdx.x;
    if (id >= W_TOT) return;
    float val;
    if (id < O_PROJ) {
        const int t = id;
        const int j = t & 7, l = (t >> 3) & 63, rem = t >> 9;
        const int ks = rem % 6, n = (rem / 6) % 9, h = rem / 54;
        const int k = ks * 32 + (l >> 4) * 8 + j;
        const int scol = n * 16 + (l & 15);
        const int col = (scol / 48) * 192 + h * 48 + (scol % 48);
        val = qkv_w[k * 576 + col];
    } else if (id < O_W1) {
        const int t = id - O_PROJ;
        const int j = t & 7, l = (t >> 3) & 63, rem = t >> 9;
        const int ks = rem % 6, n = rem / 6;
        const int k = ks * 32 + (l >> 4) * 8 + j;
        val = proj_w[k * 192 + n * 16 + (l & 15)];
    } else if (id < O_W2) {
        const int t = id - O_W1;
        const int j = t & 7, l = (t >> 3) & 63, rem = t >> 9;
        const int ks = rem % 6, n = rem / 6;
        const int k = ks * 32 + (l >> 4) * 8 + j;
        val = w1[k * 768 + n * 16 + (l & 15)];
    } else {
        const int t = id - O_W2;
        const int j = t & 7, l = (t >> 3) & 63, rem = t >> 9;
        const int ks = rem % 24, n = rem / 24;
        const int k = ks * 32 + (l >> 4) * 8 + j;
        val = w2[k * 192 + n * 16 + (l & 15)];
    }
    wf[id] = f2b(val);
}

// ---- LayerNorm over 192 channels, bf16 LDS src -> bf16 LDS dst ----
__device__ __forceinline__ void ln_pass(const unsigned short* src, unsigned short* dst,
                                        float* red, const float* __restrict__ gg,
                                        const float* __restrict__ bb, int tid)
{
    const int t = tid & 63, qd = tid >> 6;
    const int c0 = qd * 48;
    const unsigned short* sp = src + t * 200 + c0;
    float s = 0.f, s2 = 0.f;
    #pragma unroll
    for (int i = 0; i < 6; ++i) {
        uint4 r = *reinterpret_cast<const uint4*>(sp + i * 8);
        float v[8]; unpack8(r, v);
        #pragma unroll
        for (int e = 0; e < 8; ++e) { s += v[e]; s2 += v[e] * v[e]; }
    }
    red[t * 8 + qd] = s;
    red[t * 8 + 4 + qd] = s2;
    __syncthreads();
    const float mu = (red[t*8+0] + red[t*8+1] + red[t*8+2] + red[t*8+3]) * (1.f / 192.f);
    const float ms = (red[t*8+4] + red[t*8+5] + red[t*8+6] + red[t*8+7]) * (1.f / 192.f);
    const float rsig = rsqrtf(ms - mu * mu + 1e-5f);
    unsigned short* dp = dst + t * 200 + c0;
    #pragma unroll
    for (int i = 0; i < 6; ++i) {
        uint4 r = *reinterpret_cast<const uint4*>(sp + i * 8);
        float v[8]; unpack8(r, v);
        unsigned int o[4];
        #pragma unroll
        for (int e = 0; e < 4; ++e) {
            const int c = c0 + i * 8 + 2 * e;
            const unsigned short lo = f2b((v[2*e]   - mu) * rsig * gg[c]   + bb[c]);
            const unsigned short hi = f2b((v[2*e+1] - mu) * rsig * gg[c+1] + bb[c+1]);
            o[e] = (unsigned int)lo | ((unsigned int)hi << 16);
        }
        uint4 w4; w4.x = o[0]; w4.y = o[1]; w4.z = o[2]; w4.w = o[3];
        *reinterpret_cast<uint4*>(dp + i * 8) = w4;
    }
    __syncthreads();
}

__global__ __launch_bounds__(256, 2)
void swin_mfma(const float* __restrict__ x,
               const float* __restrict__ bias_tab,
               const float* __restrict__ qkv_b, const float* __restrict__ proj_b,
               const float* __restrict__ n1g, const float* __restrict__ n1b,
               const float* __restrict__ n2g, const float* __restrict__ n2b,
               const float* __restrict__ b1, const float* __restrict__ b2,
               const unsigned short* __restrict__ wf,
               float* __restrict__ out)
{
    __shared__ unsigned short sA[64 * 200];   // xn1 -> x1 (bf16)
    __shared__ unsigned short sB[64 * 200];   // x_raw -> attn-out -> xn2 -> x2
    __shared__ unsigned short sH[13440];      // q[64][72] | k[64][72] | vt[48][88]; alias hidden[64][200]
    __shared__ __align__(16) char sRB[2048];  // red (float[64][8]) / bias (ushort[900])

    float* s_red = reinterpret_cast<float*>(sRB);
    unsigned short* s_bias = reinterpret_cast<unsigned short*>(sRB);

    const int tid = threadIdx.x;
    const int l   = tid & 63;
    const int w   = tid >> 6;
    const int g   = l >> 4;
    const int li  = l & 15;

    const int wid  = blockIdx.x;
    const int b    = wid >> 8;
    const int nwin = wid & 255;
    const int wh   = nwin >> 4, ww = nwin & 15;

    // per-thread token coords for load/store passes
    const int ty = l >> 3, tx = l & 7;
    const int oh = (wh * 8 + ty + 4) & 127;
    const int ow = (ww * 8 + tx + 4) & 127;
    const int xoff = (oh << 7) + ow;

    // ---- zero pad cols 48..63 of q,k ----
    #pragma unroll
    for (int i = 0; i < 8; ++i) {
        const int e = i * 256 + tid;           // < 2048
        const int a = e >> 10;                 // 0 = q, 1 = k
        const int r = (e & 1023) >> 4;
        const int c = 48 + (e & 15);
        sH[a * 4608 + r * 72 + c] = 0;
    }

    // ---- load shifted window -> sB (bf16) ----
    #pragma unroll 4
    for (int i = 0; i < 48; ++i) {
        const int c = i * 4 + w;
        sB[l * 200 + c] = f2b(x[((b * 192 + c) << 14) + xoff]);
    }
    __syncthreads();

    // ---- LN1: sB -> sA ----
    ln_pass(sB, sA, s_red, n1g, n1b, tid);

    // ---- bias table -> LDS (s_red region now dead until LN2) ----
    for (int i = tid; i < 900; i += 256) s_bias[i] = f2b(bias_tab[i]);

    // ---- hoisted attention lane constants ----
    const int qtok = 16 * w + li;
    const int qy = qtok >> 3, qx = qtok & 7;
    const int rq = token_region(wh, ww, qtok);
    int bidx[16];
    unsigned int maskb = 0;
    #pragma unroll
    for (int mt = 0; mt < 4; ++mt)
        #pragma unroll
        for (int ri = 0; ri < 4; ++ri) {
            const int k = mt * 16 + g * 4 + ri;
            const int ky = k >> 3, kx = k & 7;
            bidx[mt * 4 + ri] = (qy - ky + 7) * 15 + (qx - kx + 7);
            if (token_region(wh, ww, k) != rq) maskb |= 1u << (mt * 4 + ri);
        }

    // ================= attention heads =================
    for (int h = 0; h < 4; ++h) {
        // ---- QKV GEMM: [64x192(bf16 sA)] @ [192x144] ----
        {
            f32x4 acc[3][4];
            #pragma unroll
            for (int tt = 0; tt < 3; ++tt)
                #pragma unroll
                for (int mt = 0; mt < 4; ++mt) acc[tt][mt] = (f32x4)0.f;
            #pragma unroll
            for (int ks = 0; ks < 6; ++ks) {
                bf16x8 af[4];
                #pragma unroll
                for (int mt = 0; mt < 4; ++mt)
                    af[mt] = ldfrag(&sA[(mt * 16 + li) * 200 + ks * 32 + g * 8]);
                #pragma unroll
                for (int tt = 0; tt < 3; ++tt) {
                    if (tt == 2 && w != 0) continue;
                    const int n = (tt == 2) ? 8 : w + tt * 4;
                    bf16x8 bf = ldfrag(&wf[O_QKV + (((h * 9 + n) * 6 + ks) << 9) + l * 8]);
                    #pragma unroll
                    for (int mt = 0; mt < 4; ++mt) acc[tt][mt] = MFMA(af[mt], bf, acc[tt][mt]);
                }
            }
            #pragma unroll
            for (int tt = 0; tt < 3; ++tt) {
                if (tt == 2 && w != 0) continue;
                const int n = (tt == 2) ? 8 : w + tt * 4;
                const int scol = n * 16 + li;
                const int arr = scol / 48, d = scol % 48;
                const float qb = qkv_b[arr * 192 + h * 48 + d];
                if (arr < 2) {
                    unsigned short* dst = &sH[arr * 4608];
                    #pragma unroll
                    for (int mt = 0; mt < 4; ++mt)
                        #pragma unroll
                        for (int ri = 0; ri < 4; ++ri)
                            dst[(mt * 16 + g * 4 + ri) * 72 + d] = f2b(acc[tt][mt][ri] + qb);
                } else {
                    #pragma unroll
                    for (int mt = 0; mt < 4; ++mt) {
                        uint2 u;
                        u.x = (unsigned int)f2b(acc[tt][mt][0] + qb) | ((unsigned int)f2b(acc[tt][mt][1] + qb) << 16);
                        u.y = (unsigned int)f2b(acc[tt][mt][2] + qb) | ((unsigned int)f2b(acc[tt][mt][3] + qb) << 16);
                        *reinterpret_cast<uint2*>(&sH[9216 + d * 88 + mt * 16 + g * 4]) = u;
                    }
                }
            }
        }
        __syncthreads();

        // ---- attention (wave-local, register softmax) ----
        {
            f32x4 sc[4];
            #pragma unroll
            for (int mt = 0; mt < 4; ++mt) sc[mt] = (f32x4)0.f;
            #pragma unroll
            for (int ks = 0; ks < 2; ++ks) {
                bf16x8 bq = ldfrag(&sH[(16 * w + li) * 72 + ks * 32 + g * 8]);
                #pragma unroll
                for (int mt = 0; mt < 4; ++mt) {
                    bf16x8 ak = ldfrag(&sH[4608 + (mt * 16 + li) * 72 + ks * 32 + g * 8]);
                    sc[mt] = MFMA(ak, bq, sc[mt]);   // S^T = K @ Q^T
                }
            }
            float p[4][4];
            float m = -3.0e38f;
            #pragma unroll
            for (int mt = 0; mt < 4; ++mt)
                #pragma unroll
                for (int ri = 0; ri < 4; ++ri) {
                    const int bit = mt * 4 + ri;
                    const float add = ((maskb >> bit) & 1u) ? -100.f
                                      : b2f(s_bias[h * 225 + bidx[bit]]);
                    const float s = sc[mt][ri] * SCALE + add;
                    p[mt][ri] = s;
                    m = fmaxf(m, s);
                }
            m = fmaxf(m, __shfl_xor(m, 16));
            m = fmaxf(m, __shfl_xor(m, 32));
            float rs = 0.f;
            #pragma unroll
            for (int mt = 0; mt < 4; ++mt)
                #pragma unroll
                for (int ri = 0; ri < 4; ++ri) {
                    const float e = __expf(p[mt][ri] - m);
                    p[mt][ri] = e; rs += e;
                }
            rs += __shfl_xor(rs, 16);
            rs += __shfl_xor(rs, 32);
            const float rcp = __builtin_amdgcn_rcpf(rs);

            f32x4 oa[3];
            #pragma unroll
            for (int mt = 0; mt < 3; ++mt) oa[mt] = (f32x4)0.f;
            #pragma unroll
            for (int ks = 0; ks < 2; ++ks) {
                union { unsigned short us[8]; bf16x8 v; } bp;
                #pragma unroll
                for (int jj = 0; jj < 8; ++jj) {
                    const int srcLane = li + 16 * (2 * (g & 1) + (jj >> 2));
                    const float va = __shfl(p[ks * 2 + 0][jj & 3], srcLane);
                    const float vb = __shfl(p[ks * 2 + 1][jj & 3], srcLane);
                    bp.us[jj] = f2b((g >> 1) ? vb : va);
                }
                #pragma unroll
                for (int mt = 0; mt < 3; ++mt) {
                    bf16x8 av = ldfrag(&sH[9216 + (mt * 16 + li) * 88 + ks * 32 + g * 8]);
                    oa[mt] = MFMA(av, bp.v, oa[mt]);   // out^T = Vt @ P^T
                }
            }
            #pragma unroll
            for (int mt = 0; mt < 3; ++mt) {
                uint2 u;
                u.x = (unsigned int)f2b(oa[mt][0] * rcp) | ((unsigned int)f2b(oa[mt][1] * rcp) << 16);
                u.y = (unsigned int)f2b(oa[mt][2] * rcp) | ((unsigned int)f2b(oa[mt][3] * rcp) << 16);
                *reinterpret_cast<uint2*>(&sB[qtok * 200 + h * 48 + mt * 16 + g * 4]) = u;
            }
        }
        __syncthreads();
    }

    // ---- proj GEMM: sB @ proj_w -> sA (bf16, + proj_b) ----
    {
        f32x4 pa[3][4];
        #pragma unroll
        for (int tt = 0; tt < 3; ++tt)
            #pragma unroll
            for (int mt = 0; mt < 4; ++mt) pa[tt][mt] = (f32x4)0.f;
        #pragma unroll
        for (int ks = 0; ks < 6; ++ks) {
            bf16x8 af[4];
            #pragma unroll
            for (int mt = 0; mt < 4; ++mt)
                af[mt] = ldfrag(&sB[(mt * 16 + li) * 200 + ks * 32 + g * 8]);
            #pragma unroll
            for (int tt = 0; tt < 3; ++tt) {
                bf16x8 bf = ldfrag(&wf[O_PROJ + (((3 * w + tt) * 6 + ks) << 9) + l * 8]);
                #pragma unroll
                for (int mt = 0; mt < 4; ++mt) pa[tt][mt] = MFMA(af[mt], bf, pa[tt][mt]);
            }
        }
        #pragma unroll
        for (int tt = 0; tt < 3; ++tt) {
            const int col = (3 * w + tt) * 16 + li;
            const float pb = proj_b[col];
            #pragma unroll
            for (int mt = 0; mt < 4; ++mt)
                #pragma unroll
                for (int ri = 0; ri < 4; ++ri)
                    sA[(mt * 16 + g * 4 + ri) * 200 + col] = f2b(pa[tt][mt][ri] + pb);
        }
    }
    __syncthreads();

    // ---- shortcut add: sA += x (global re-read) ----
    #pragma unroll 4
    for (int i = 0; i < 48; ++i) {
        const int c = i * 4 + w;
        const int o = l * 200 + c;
        sA[o] = f2b(b2f(sA[o]) + x[((b * 192 + c) << 14) + xoff]);
    }
    __syncthreads();

    // ---- LN2: sA -> sB ----
    ln_pass(sA, sB, s_red, n2g, n2b, tid);

    // ---- MLP ----
    f32x4 ma[3][4];
    #pragma unroll
    for (int tt = 0; tt < 3; ++tt)
        #pragma unroll
        for (int mt = 0; mt < 4; ++mt) ma[tt][mt] = (f32x4)0.f;

    for (int ch = 0; ch < 4; ++ch) {
        // MLP1: hidden = gelu(sB @ w1 + b1), chunk of 192 units
        {
            f32x4 ha[3][4];
            #pragma unroll
            for (int tt = 0; tt < 3; ++tt)
                #pragma unroll
                for (int mt = 0; mt < 4; ++mt) ha[tt][mt] = (f32x4)0.f;
            #pragma unroll
            for (int ks = 0; ks < 6; ++ks) {
                bf16x8 af[4];
                #pragma unroll
                for (int mt = 0; mt < 4; ++mt)
                    af[mt] = ldfrag(&sB[(mt * 16 + li) * 200 + ks * 32 + g * 8]);
                #pragma unroll
                for (int tt = 0; tt < 3; ++tt) {
                    bf16x8 bf = ldfrag(&wf[O_W1 + (((ch * 12 + 3 * w + tt) * 6 + ks) << 9) + l * 8]);
                    #pragma unroll
                    for (int mt = 0; mt < 4; ++mt) ha[tt][mt] = MFMA(af[mt], bf, ha[tt][mt]);
                }
            }
            #pragma unroll
            for (int tt = 0; tt < 3; ++tt) {
                const int colL = (3 * w + tt) * 16 + li;
                const float bb = b1[ch * 192 + colL];
                #pragma unroll
                for (int mt = 0; mt < 4; ++mt)
                    #pragma unroll
                    for (int ri = 0; ri < 4; ++ri)
                        sH[(mt * 16 + g * 4 + ri) * 200 + colL] = f2b(gelu_f(ha[tt][mt][ri] + bb));
            }
        }
        __syncthreads();
        // MLP2 partial: ma += hidden @ w2[chunk]
        #pragma unroll
        for (int ks = 0; ks < 6; ++ks) {
            bf16x8 af[4];
            #pragma unroll
            for (int mt = 0; mt < 4; ++mt)
                af[mt] = ldfrag(&sH[(mt * 16 + li) * 200 + ks * 32 + g * 8]);
            #pragma unroll
            for (int tt = 0; tt < 3; ++tt) {
                bf16x8 bf = ldfrag(&wf[O_W2 + (((3 * w + tt) * 24 + ch * 6 + ks) << 9) + l * 8]);
                #pragma unroll
                for (int mt = 0; mt < 4; ++mt) ma[tt][mt] = MFMA(af[mt], bf, ma[tt][mt]);
            }
        }
        __syncthreads();
    }

    // ---- final epilogue: x2 = x1 + mlp + b2 -> sB ----
    #pragma unroll
    for (int tt = 0; tt < 3; ++tt) {
        const int col = (3 * w + tt) * 16 + li;
        const float bb = b2[col];
        #pragma unroll
        for (int mt = 0; mt < 4; ++mt)
            #pragma unroll
            for (int ri = 0; ri < 4; ++ri) {
                const int row = mt * 16 + g * 4 + ri;
                sB[row * 200 + col] = f2b(ma[tt][mt][ri] + bb + b2f(sA[row * 200 + col]));
            }
    }
    __syncthreads();

    // ---- write out (window reverse + roll back), coalesced ----
    #pragma unroll 4
    for (int i = 0; i < 48; ++i) {
        const int c = i * 4 + w;
        out[((b * 192 + c) << 14) + xoff] = b2f(sB[l * 200 + c]);
    }
}

} // namespace

extern "C" void kernel_launch(void* const* d_in, const int* in_sizes, int n_in,
                              void* d_out, int out_size, void* d_ws, size_t ws_size,
                              hipStream_t stream) {
    (void)in_sizes; (void)n_in; (void)ws_size; (void)out_size;
    const float* x   = (const float*)d_in[0];
    const float* bt  = (const float*)d_in[1];
    const float* qw  = (const float*)d_in[2];
    const float* qb  = (const float*)d_in[3];
    const float* pw  = (const float*)d_in[4];
    const float* pb  = (const float*)d_in[5];
    const float* g1  = (const float*)d_in[6];
    const float* be1 = (const float*)d_in[7];
    const float* g2  = (const float*)d_in[8];
    const float* be2 = (const float*)d_in[9];
    const float* w1  = (const float*)d_in[10];
    const float* bb1 = (const float*)d_in[11];
    const float* w2  = (const float*)d_in[12];
    const float* bb2 = (const float*)d_in[13];

    unsigned short* wf = (unsigned short*)d_ws;

    convert_weights<<<(W_TOT + 255) / 256, 256, 0, stream>>>(qw, pw, w1, w2, wf);
    swin_mfma<<<NB * NWIN, 256, 0, stream>>>(
        x, bt, qb, pb, g1, be1, g2, be2, bb1, bb2, wf, (float*)d_out);
}